// Round 1
// baseline (1149.983 us; speedup 1.0000x reference)
//
#include <hip/hip_runtime.h>
#include <math.h>

#define NSIG   1023
#define BATCH  16
#define FT     1024          // F_BINS == T == 1024
#define KW     320           // truncated window taps, d in [-160, 159]
#define RHALF  160
#define XPAD   1344          // 160 + 1023 + 159 (+2 pad to mult of 4)
#define HID    128

// ws layout (float offsets)
#define OFF_XCP  0u                       // 16*1344 = 21504
#define OFF_G    21504u                   // 320
#define OFF_ECT  21824u                   // 320*1024 = 327680 (cos, [k][f])
#define OFF_EST  (21824u + 327680u)       // 320*1024 (sin, [k][f])
#define OFF_HRAW (21824u + 2u*327680u)    // 2048  (fc1 accum, b-major: b*128+j)

// ---------------- K0: per-batch mean removal into zero-padded buffer ----------
__global__ void k_prep(const float* __restrict__ x, float* __restrict__ ws) {
    int b = blockIdx.x;
    __shared__ float red[256];
    float s = 0.f;
    for (int i = threadIdx.x; i < NSIG; i += 256) s += x[b * NSIG + i];
    red[threadIdx.x] = s;
    __syncthreads();
    for (int o = 128; o > 0; o >>= 1) {
        if (threadIdx.x < o) red[threadIdx.x] += red[threadIdx.x + o];
        __syncthreads();
    }
    float mean = red[0] * (1.0f / NSIG);
    float* xcp = ws + OFF_XCP + b * XPAD;
    for (int i = threadIdx.x; i < XPAD; i += 256) {
        int n = i - RHALF;
        xcp[i] = (n >= 0 && n < NSIG) ? (x[b * NSIG + n] - mean) : 0.f;
    }
}

// ---------------- K1: sincos tables (exact integer phase reduction) -----------
__global__ void k_tables(const float* __restrict__ lambd, float* __restrict__ ws) {
    int bid = blockIdx.x;
    if (bid == 1280) {
        float sigma = fabsf(lambd[0]);
        float inv2s2 = 0.5f / (sigma * sigma);
        for (int i = threadIdx.x; i < KW; i += 256) {
            float d = (float)(i - RHALF);
            ws[OFF_G + i] = expf(-d * d * inv2s2);
        }
        for (int i = threadIdx.x; i < 2048; i += 256) ws[OFF_HRAW + i] = 0.f;
        return;
    }
    int idx = bid * 256 + threadIdx.x;       // 0 .. 327679
    int k = idx >> 10, f = idx & 1023;
    int d = k - RHALF;
    int p = f * d;                           // |p| <= 163680, fits int
    int m = p % 2046; if (m < 0) m += 2046;  // exact phase mod 2pi
    double ang = (double)m * (6.283185307179586476925286766559 / 2046.0);
    double sv, cv;
    sincos(ang, &sv, &cv);
    ws[OFF_ECT + idx] = (float)cv;
    ws[OFF_EST + idx] = (float)sv;
}

// ---------------- K2: spectrogram GEMM  S[b][f][t] = re^2 + im^2 --------------
// grid (16 t-tiles, 16 f-tiles, 16 b), 256 threads, 64x64 tile, 4x4 per thread
__global__ __launch_bounds__(256) void k_spec(const float* __restrict__ ws,
                                              float* __restrict__ out) {
    __shared__ float xseg[384];
    __shared__ float gsh[KW];
    __shared__ float Ac[16][64], As[16][64], By[16][64];

    int t0 = blockIdx.x * 64, f0 = blockIdx.y * 64, b = blockIdx.z;
    int tid = threadIdx.x;
    const float* xcp = ws + OFF_XCP + b * XPAD;

    if (tid < 96) *(float4*)&xseg[tid * 4] = *(const float4*)&xcp[t0 + tid * 4];
    if (tid >= 96 && tid < 176) {
        int i = (tid - 96) * 4;
        *(float4*)&gsh[i] = *(const float4*)&ws[OFF_G + i];
    }
    __syncthreads();

    float re[4][4] = {{0}}, im[4][4] = {{0}};
    int tn = tid & 15, fm = tid >> 4;        // tn: t sub-tile (coalesced stores)
    int kk = tid >> 4, cc = (tid & 15) * 4;  // staging coords

    for (int k0 = 0; k0 < KW; k0 += 16) {
        float4 ec = *(const float4*)&ws[OFF_ECT + (size_t)(k0 + kk) * 1024 + f0 + cc];
        float4 es = *(const float4*)&ws[OFF_EST + (size_t)(k0 + kk) * 1024 + f0 + cc];
        float g = gsh[k0 + kk];
        int xb = cc + k0 + kk;
        float4 y = { xseg[xb] * g, xseg[xb + 1] * g, xseg[xb + 2] * g, xseg[xb + 3] * g };
        // prev-iter compute ended with a barrier, safe to overwrite
        *(float4*)&Ac[kk][cc] = ec;
        *(float4*)&As[kk][cc] = es;
        *(float4*)&By[kk][cc] = y;
        __syncthreads();
        #pragma unroll
        for (int k = 0; k < 16; k++) {
            float4 a4 = *(float4*)&Ac[k][fm * 4];
            float4 s4 = *(float4*)&As[k][fm * 4];
            float4 y4 = *(float4*)&By[k][tn * 4];
            float av[4] = { a4.x, a4.y, a4.z, a4.w };
            float sv[4] = { s4.x, s4.y, s4.z, s4.w };
            float yv[4] = { y4.x, y4.y, y4.z, y4.w };
            #pragma unroll
            for (int i = 0; i < 4; i++)
                #pragma unroll
                for (int j = 0; j < 4; j++) {
                    re[i][j] += av[i] * yv[j];
                    im[i][j] += sv[i] * yv[j];
                }
        }
        __syncthreads();
    }

    float* dS = out + 160;
    #pragma unroll
    for (int i = 0; i < 4; i++) {
        int row = f0 + fm * 4 + i;
        float4 v = { re[i][0] * re[i][0] + im[i][0] * im[i][0],
                     re[i][1] * re[i][1] + im[i][1] * im[i][1],
                     re[i][2] * re[i][2] + im[i][2] * im[i][2],
                     re[i][3] * re[i][3] + im[i][3] * im[i][3] };
        *(float4*)&dS[((size_t)b << 20) + (size_t)row * 1024 + t0 + tn * 4] = v;
    }
}

// ---------------- K3: fc1 partial  hraw[b*128+j] += sum_i S[b][i]*W1[j][i] ----
// grid 512 blocks, each block 2048 features (2 subs of 1024), W1 streamed once.
__global__ __launch_bounds__(256) void k_fc1(const float* __restrict__ S,
                                             const float* __restrict__ W1,
                                             float* __restrict__ hraw) {
    int tid = threadIdx.x;
    int lane = tid & 63;
    for (int sub = 0; sub < 2; sub++) {
        size_t fbase = (size_t)blockIdx.x * 2048 + (size_t)sub * 1024 + tid * 4;
        float4 s4[16];
        #pragma unroll
        for (int b = 0; b < 16; b++)
            s4[b] = *(const float4*)&S[((size_t)b << 20) + fbase];
        for (int jg = 0; jg < 32; jg++) {
            float v[64];
            #pragma unroll
            for (int jj = 0; jj < 4; jj++) {
                float4 w = *(const float4*)&W1[((size_t)(jg * 4 + jj) << 20) + fbase];
                #pragma unroll
                for (int b = 0; b < 16; b++) {
                    v[b * 4 + jj] = w.x * s4[b].x + w.y * s4[b].y +
                                    w.z * s4[b].z + w.w * s4[b].w;
                }
            }
            // multi-value wave tree-reduce: lane L ends with total of value L
            #pragma unroll
            for (int off = 32; off >= 1; off >>= 1) {
                bool hi = (lane & off) != 0;
                #pragma unroll
                for (int i = 0; i < off; i++) {
                    float a = v[i], c = v[i + off];
                    float send = hi ? a : c;
                    float keep = hi ? c : a;
                    v[i] = keep + __shfl_xor(send, off);
                }
            }
            // value index = lane: b = lane>>2, jj = lane&3
            atomicAdd(&hraw[(lane >> 2) * HID + jg * 4 + (lane & 3)], v[0]);
        }
    }
}

// ---------------- K4: bias+relu+fc2 head --------------------------------------
__global__ void k_head(const float* __restrict__ hraw, const float* __restrict__ b1,
                       const float* __restrict__ W2, const float* __restrict__ b2,
                       float* __restrict__ out) {
    __shared__ float hl[2048];
    int tid = threadIdx.x;
    for (int p = tid; p < 2048; p += 256) {
        float hv = hraw[p] + b1[p & 127];
        hl[p] = hv > 0.f ? hv : 0.f;
    }
    __syncthreads();
    if (tid < 160) {
        int b = tid / 10, c = tid - b * 10;
        float s = b2[c];
        for (int j = 0; j < 128; j++) s += hl[b * 128 + j] * W2[c * 128 + j];
        out[b * 10 + c] = s;
    }
}

extern "C" void kernel_launch(void* const* d_in, const int* in_sizes, int n_in,
                              void* d_out, int out_size, void* d_ws, size_t ws_size,
                              hipStream_t stream) {
    const float* x     = (const float*)d_in[0];
    const float* lambd = (const float*)d_in[1];
    const float* W1    = (const float*)d_in[2];
    const float* b1    = (const float*)d_in[3];
    const float* W2    = (const float*)d_in[4];
    const float* b2    = (const float*)d_in[5];
    float* out = (float*)d_out;
    float* ws  = (float*)d_ws;

    hipLaunchKernelGGL(k_prep,   dim3(16),          dim3(256), 0, stream, x, ws);
    hipLaunchKernelGGL(k_tables, dim3(1281),        dim3(256), 0, stream, lambd, ws);
    hipLaunchKernelGGL(k_spec,   dim3(16, 16, 16),  dim3(256), 0, stream, ws, out);
    hipLaunchKernelGGL(k_fc1,    dim3(512),         dim3(256), 0, stream,
                       out + 160, W1, ws + OFF_HRAW);
    hipLaunchKernelGGL(k_head,   dim3(1),           dim3(256), 0, stream,
                       ws + OFF_HRAW, b1, W2, b2, out);
}

// Round 3
// 423.567 us; speedup vs baseline: 2.7150x; 2.7150x over previous
//
#include <hip/hip_runtime.h>
#include <math.h>

#define NSIG   1023
#define BATCH  16
#define FT     1024          // F_BINS == T == 1024
#define KW     320           // truncated window taps, d in [-160, 159]
#define RHALF  160
#define XPAD   1344          // 160 + 1023 + 159 (+2 pad to mult of 4)
#define HID    128

// ws layout (float offsets)
#define OFF_XCP  0u                       // 16*1344 = 21504
#define OFF_G    21504u                   // 320
#define OFF_ECT  21824u                   // 320*1024 = 327680 (cos, [k][f])
#define OFF_EST  (21824u + 327680u)       // 320*1024 (sin, [k][f])
#define OFF_HRAW (21824u + 2u*327680u)    // 2048  (fc1 accum, b-major: b*128+j)

typedef int   i32x4 __attribute__((ext_vector_type(4)));
typedef float f32x4 __attribute__((ext_vector_type(4)));

// ---------------- K0: per-batch mean removal into zero-padded buffer ----------
__global__ void k_prep(const float* __restrict__ x, float* __restrict__ ws) {
    int b = blockIdx.x;
    __shared__ float red[256];
    float s = 0.f;
    for (int i = threadIdx.x; i < NSIG; i += 256) s += x[b * NSIG + i];
    red[threadIdx.x] = s;
    __syncthreads();
    for (int o = 128; o > 0; o >>= 1) {
        if (threadIdx.x < o) red[threadIdx.x] += red[threadIdx.x + o];
        __syncthreads();
    }
    float mean = red[0] * (1.0f / NSIG);
    float* xcp = ws + OFF_XCP + b * XPAD;
    for (int i = threadIdx.x; i < XPAD; i += 256) {
        int n = i - RHALF;
        xcp[i] = (n >= 0 && n < NSIG) ? (x[b * NSIG + n] - mean) : 0.f;
    }
}

// ---------------- K1: sincos tables (exact integer phase reduction) -----------
__global__ void k_tables(const float* __restrict__ lambd, float* __restrict__ ws) {
    int bid = blockIdx.x;
    if (bid == 1280) {
        float sigma = fabsf(lambd[0]);
        float inv2s2 = 0.5f / (sigma * sigma);
        for (int i = threadIdx.x; i < KW; i += 256) {
            float d = (float)(i - RHALF);
            ws[OFF_G + i] = expf(-d * d * inv2s2);
        }
        for (int i = threadIdx.x; i < 2048; i += 256) ws[OFF_HRAW + i] = 0.f;
        return;
    }
    int idx = bid * 256 + threadIdx.x;       // 0 .. 327679
    int k = idx >> 10, f = idx & 1023;
    int d = k - RHALF;
    int p = f * d;                           // |p| <= 163680, fits int
    int m = p % 2046; if (m < 0) m += 2046;  // exact phase mod 2pi
    double ang = (double)m * (6.283185307179586476925286766559 / 2046.0);
    double sv, cv;
    sincos(ang, &sv, &cv);
    ws[OFF_ECT + idx] = (float)cv;
    ws[OFF_EST + idx] = (float)sv;
}

// ---------------- K2: spectrogram GEMM  S[b][f][t] = re^2 + im^2 --------------
// grid (16 t-tiles, 16 f-tiles, 16 b), 256 threads, 64x64 tile, 4x4 per thread
__global__ __launch_bounds__(256) void k_spec(const float* __restrict__ ws,
                                              float* __restrict__ out) {
    __shared__ float xseg[384];
    __shared__ float gsh[KW];
    __shared__ float Ac[16][64], As[16][64], By[16][64];

    int t0 = blockIdx.x * 64, f0 = blockIdx.y * 64, b = blockIdx.z;
    int tid = threadIdx.x;
    const float* xcp = ws + OFF_XCP + b * XPAD;

    if (tid < 96) *(float4*)&xseg[tid * 4] = *(const float4*)&xcp[t0 + tid * 4];
    if (tid >= 96 && tid < 176) {
        int i = (tid - 96) * 4;
        *(float4*)&gsh[i] = *(const float4*)&ws[OFF_G + i];
    }
    __syncthreads();

    float re[4][4] = {{0}}, im[4][4] = {{0}};
    int tn = tid & 15, fm = tid >> 4;        // tn: t sub-tile (coalesced stores)
    int kk = tid >> 4, cc = (tid & 15) * 4;  // staging coords

    for (int k0 = 0; k0 < KW; k0 += 16) {
        float4 ec = *(const float4*)&ws[OFF_ECT + (size_t)(k0 + kk) * 1024 + f0 + cc];
        float4 es = *(const float4*)&ws[OFF_EST + (size_t)(k0 + kk) * 1024 + f0 + cc];
        float g = gsh[k0 + kk];
        int xb = cc + k0 + kk;
        float4 y = { xseg[xb] * g, xseg[xb + 1] * g, xseg[xb + 2] * g, xseg[xb + 3] * g };
        // prev-iter compute ended with a barrier, safe to overwrite
        *(float4*)&Ac[kk][cc] = ec;
        *(float4*)&As[kk][cc] = es;
        *(float4*)&By[kk][cc] = y;
        __syncthreads();
        #pragma unroll
        for (int k = 0; k < 16; k++) {
            float4 a4 = *(float4*)&Ac[k][fm * 4];
            float4 s4 = *(float4*)&As[k][fm * 4];
            float4 y4 = *(float4*)&By[k][tn * 4];
            float av[4] = { a4.x, a4.y, a4.z, a4.w };
            float sv[4] = { s4.x, s4.y, s4.z, s4.w };
            float yv[4] = { y4.x, y4.y, y4.z, y4.w };
            #pragma unroll
            for (int i = 0; i < 4; i++)
                #pragma unroll
                for (int j = 0; j < 4; j++) {
                    re[i][j] += av[i] * yv[j];
                    im[i][j] += sv[i] * yv[j];
                }
        }
        __syncthreads();
    }

    float* dS = out + 160;
    #pragma unroll
    for (int i = 0; i < 4; i++) {
        int row = f0 + fm * 4 + i;
        float4 v = { re[i][0] * re[i][0] + im[i][0] * im[i][0],
                     re[i][1] * re[i][1] + im[i][1] * im[i][1],
                     re[i][2] * re[i][2] + im[i][2] * im[i][2],
                     re[i][3] * re[i][3] + im[i][3] * im[i][3] };
        *(float4*)&dS[((size_t)b << 20) + (size_t)row * 1024 + t0 + tn * 4] = v;
    }
}

// ---------------- K3: fc1 via MFMA split-K ------------------------------------
// h[b,j] = sum_i S[b,i] * W1[j,i], K = 1M. 1024 blocks x 4 waves.
// Wave: jg = wave>>1 (j-half of 64), k-stripe ks = blockIdx*2 + (wave&1),
// 512 features per stripe = 16 MFMA k-steps. C/D layout (m89): col=lane&15,
// row=(lane>>4)*4+reg. A/B k-permutation cancels (full-K contraction).
static __device__ __forceinline__ unsigned bfbits(float v) {
    unsigned u = __builtin_bit_cast(unsigned, v);
    return (u + 0x7fffu + ((u >> 16) & 1u)) >> 16;   // RNE round to bf16
}
static __device__ __forceinline__ int packbf2(float lo, float hi) {
    return (int)(bfbits(lo) | (bfbits(hi) << 16));
}
static __device__ __forceinline__ i32x4 pack8(float4 a, float4 b) {
    i32x4 r;
    r.x = packbf2(a.x, a.y); r.y = packbf2(a.z, a.w);
    r.z = packbf2(b.x, b.y); r.w = packbf2(b.z, b.w);
    return r;
}

__global__ __launch_bounds__(256, 4) void k_fc1(const float* __restrict__ S,
                                                const float* __restrict__ W1,
                                                float* __restrict__ hraw) {
    __shared__ float red[4][1024];
    int tid = threadIdx.x;
    int wave = tid >> 6, lane = tid & 63;
    int jg = wave >> 1;                          // 0..1 : j-half
    int ks = (blockIdx.x << 1) | (wave & 1);     // 0..2047 k-stripe
    int bq = lane >> 4, lo = lane & 15;

    const float* Sp = S + (size_t)lo * (1u << 20) + (size_t)ks * 512 + bq * 8;
    const float* Wp = W1 + (size_t)(jg * 64 + lo) * (1u << 20) + (size_t)ks * 512 + bq * 8;

    f32x4 acc0 = {0.f,0.f,0.f,0.f}, acc1 = acc0, acc2 = acc0, acc3 = acc0;

    for (int step = 0; step < 16; step++) {
        const float* sp = Sp + step * 32;
        const float* wp = Wp + step * 32;
        float4 a0 = *(const float4*)(sp);
        float4 a1 = *(const float4*)(sp + 4);
        float4 w00 = *(const float4*)(wp);
        float4 w01 = *(const float4*)(wp + 4);
        float4 w10 = *(const float4*)(wp + (1u << 24));          // +16 rows * 1M
        float4 w11 = *(const float4*)(wp + (1u << 24) + 4);
        float4 w20 = *(const float4*)(wp + (2u << 24));
        float4 w21 = *(const float4*)(wp + (2u << 24) + 4);
        float4 w30 = *(const float4*)(wp + (3u << 24));
        float4 w31 = *(const float4*)(wp + (3u << 24) + 4);
        i32x4 af = pack8(a0, a1);
        i32x4 b0 = pack8(w00, w01);
        i32x4 b1 = pack8(w10, w11);
        i32x4 b2 = pack8(w20, w21);
        i32x4 b3 = pack8(w30, w31);
        asm("v_mfma_f32_16x16x32_bf16 %0, %1, %2, %0" : "+v"(acc0) : "v"(af), "v"(b0));
        asm("v_mfma_f32_16x16x32_bf16 %0, %1, %2, %0" : "+v"(acc1) : "v"(af), "v"(b1));
        asm("v_mfma_f32_16x16x32_bf16 %0, %1, %2, %0" : "+v"(acc2) : "v"(af), "v"(b2));
        asm("v_mfma_f32_16x16x32_bf16 %0, %1, %2, %0" : "+v"(acc3) : "v"(af), "v"(b3));
    }
    asm volatile("s_nop 7\n\ts_nop 7");   // MFMA->VALU read hazard guard

    // wave-local store: red[wave][b*64 + jl], b = bq*4+r, jl = t*16+lo
    #pragma unroll
    for (int r = 0; r < 4; r++) {
        red[wave][(bq * 4 + r) * 64 +  0 + lo] = acc0[r];
        red[wave][(bq * 4 + r) * 64 + 16 + lo] = acc1[r];
        red[wave][(bq * 4 + r) * 64 + 32 + lo] = acc2[r];
        red[wave][(bq * 4 + r) * 64 + 48 + lo] = acc3[r];
    }
    __syncthreads();
    for (int p = tid; p < 2048; p += 256) {
        int g = p >> 10, idx = p & 1023;
        float v = red[g * 2][idx] + red[g * 2 + 1][idx];
        atomicAdd(&hraw[(idx >> 6) * HID + g * 64 + (idx & 63)], v);
    }
}

// ---------------- K4: bias+relu+fc2 head --------------------------------------
__global__ void k_head(const float* __restrict__ hraw, const float* __restrict__ b1,
                       const float* __restrict__ W2, const float* __restrict__ b2,
                       float* __restrict__ out) {
    __shared__ float hl[2048];
    int tid = threadIdx.x;
    for (int p = tid; p < 2048; p += 256) {
        float hv = hraw[p] + b1[p & 127];
        hl[p] = hv > 0.f ? hv : 0.f;
    }
    __syncthreads();
    if (tid < 160) {
        int b = tid / 10, c = tid - b * 10;
        float s = b2[c];
        for (int j = 0; j < 128; j++) s += hl[b * 128 + j] * W2[c * 128 + j];
        out[b * 10 + c] = s;
    }
}

extern "C" void kernel_launch(void* const* d_in, const int* in_sizes, int n_in,
                              void* d_out, int out_size, void* d_ws, size_t ws_size,
                              hipStream_t stream) {
    const float* x     = (const float*)d_in[0];
    const float* lambd = (const float*)d_in[1];
    const float* W1    = (const float*)d_in[2];
    const float* b1    = (const float*)d_in[3];
    const float* W2    = (const float*)d_in[4];
    const float* b2    = (const float*)d_in[5];
    float* out = (float*)d_out;
    float* ws  = (float*)d_ws;

    hipLaunchKernelGGL(k_prep,   dim3(16),          dim3(256), 0, stream, x, ws);
    hipLaunchKernelGGL(k_tables, dim3(1281),        dim3(256), 0, stream, lambd, ws);
    hipLaunchKernelGGL(k_spec,   dim3(16, 16, 16),  dim3(256), 0, stream, ws, out);
    hipLaunchKernelGGL(k_fc1,    dim3(1024),        dim3(256), 0, stream,
                       out + 160, W1, ws + OFF_HRAW);
    hipLaunchKernelGGL(k_head,   dim3(1),           dim3(256), 0, stream,
                       ws + OFF_HRAW, b1, W2, b2, out);
}

// Round 4
// 264.850 us; speedup vs baseline: 4.3420x; 1.5993x over previous
//
#include <hip/hip_runtime.h>
#include <math.h>

#define NSIG   1023
#define BATCH  16
#define FT     1024          // F_BINS == T == 1024
#define KW     320           // truncated window taps, d in [-160, 159]
#define RHALF  160
#define XPAD   1344          // 160 + 1023 + 159 (+2 pad to mult of 4)
#define HID    128

// ws layout (float offsets)
#define OFF_XCP  0u                       // 16*1344 = 21504
#define OFF_G    21504u                   // 320
#define OFF_HRAW 21824u                   // 2048  (fc1 accum, b-major: b*128+j)
#define OFF_TAB  23872u                   // bf16 hi/lo tables, 4 x 327680 u16
// u16 offsets within tab
#define TAB_ECH  0u
#define TAB_ECL  327680u
#define TAB_ESH  655360u
#define TAB_ESL  983040u

typedef int   i32x4 __attribute__((ext_vector_type(4)));
typedef float f32x4 __attribute__((ext_vector_type(4)));
typedef unsigned short u16;

static __device__ __forceinline__ unsigned bfbits(float v) {
    unsigned u = __builtin_bit_cast(unsigned, v);
    return (u + 0x7fffu + ((u >> 16) & 1u)) >> 16;   // RNE round to bf16
}

// ---------------- K0: per-batch mean removal into zero-padded buffer ----------
__global__ void k_prep(const float* __restrict__ x, float* __restrict__ ws) {
    int b = blockIdx.x;
    __shared__ float red[256];
    float s = 0.f;
    for (int i = threadIdx.x; i < NSIG; i += 256) s += x[b * NSIG + i];
    red[threadIdx.x] = s;
    __syncthreads();
    for (int o = 128; o > 0; o >>= 1) {
        if (threadIdx.x < o) red[threadIdx.x] += red[threadIdx.x + o];
        __syncthreads();
    }
    float mean = red[0] * (1.0f / NSIG);
    float* xcp = ws + OFF_XCP + b * XPAD;
    for (int i = threadIdx.x; i < XPAD; i += 256) {
        int n = i - RHALF;
        xcp[i] = (n >= 0 && n < NSIG) ? (x[b * NSIG + n] - mean) : 0.f;
    }
}

// ---------------- K1: hi/lo bf16 sincos tables, f-major [f][320] --------------
__global__ void k_tables(const float* __restrict__ lambd, float* __restrict__ ws) {
    int bid = blockIdx.x;
    if (bid == 1280) {
        float sigma = fabsf(lambd[0]);
        float inv2s2 = 0.5f / (sigma * sigma);
        for (int i = threadIdx.x; i < KW; i += 256) {
            float d = (float)(i - RHALF);
            ws[OFF_G + i] = expf(-d * d * inv2s2);
        }
        for (int i = threadIdx.x; i < 2048; i += 256) ws[OFF_HRAW + i] = 0.f;
        return;
    }
    int idx = bid * 256 + threadIdx.x;       // 0 .. 327679 = f*320 + k
    int f = idx / 320, k = idx - f * 320;
    int d = k - RHALF;
    int p = f * d;                           // |p| <= 163680, fits int
    int m = p % 2046; if (m < 0) m += 2046;  // exact phase mod 2pi
    double ang = (double)m * (6.283185307179586476925286766559 / 2046.0);
    double sv, cv;
    sincos(ang, &sv, &cv);
    float cf = (float)cv, sf = (float)sv;
    u16* tab = (u16*)(ws + OFF_TAB);
    unsigned chb = bfbits(cf);
    float chf = __builtin_bit_cast(float, chb << 16);
    unsigned clb = bfbits(cf - chf);
    unsigned shb = bfbits(sf);
    float shf = __builtin_bit_cast(float, shb << 16);
    unsigned slb = bfbits(sf - shf);
    tab[TAB_ECH + idx] = (u16)chb;
    tab[TAB_ECL + idx] = (u16)clb;
    tab[TAB_ESH + idx] = (u16)shb;
    tab[TAB_ESL + idx] = (u16)slb;
}

// ---------------- K2: spectrogram via split-bf16 MFMA -------------------------
// S[b][f][t] = re^2 + im^2,  re/im = sum_k E[k,f] * y[k,t],  y[k,t]=xc[t+k]g[k]
// grid (16 t-tiles, 16 f-tiles, 16 b), 4 waves; wave w owns f-strip w (16 rows),
// iterates 4 t-tiles. K chunked by 32; y hi/lo staged in XOR-swizzled LDS.
// Split product: Ah*Bh + Ah*Bl + Al*Bh (lo*lo dropped, rel err ~2^-18).
__global__ __launch_bounds__(256, 4) void k_spec(const float* __restrict__ ws,
                                                 float* __restrict__ out) {
    __shared__ float xseg[384];
    __shared__ float gsh[KW];
    __shared__ u16 yH[2048];   // swizzled t-major [64][32]
    __shared__ u16 yL[2048];

    int t0 = blockIdx.x * 64, f0 = blockIdx.y * 64, b = blockIdx.z;
    int tid = threadIdx.x;
    int wave = tid >> 6, lane = tid & 63;
    int lo = lane & 15, hi4 = lane >> 4;
    const float* xcp = ws + OFF_XCP + b * XPAD;
    const u16* tab = (const u16*)(ws + OFF_TAB);

    if (tid < 96) *(float4*)&xseg[tid * 4] = *(const float4*)&xcp[t0 + tid * 4];
    if (tid >= 96 && tid < 176) {
        int i = (tid - 96) * 4;
        *(float4*)&gsh[i] = *(const float4*)&ws[OFF_G + i];
    }

    // A-fragment pointers: row f = f0 + wave*16 + lo, 8 consecutive k at hi4*8
    size_t arow = (size_t)(f0 + wave * 16 + lo) * 320 + hi4 * 8;
    const u16* pech = tab + TAB_ECH + arow;
    const u16* pecl = tab + TAB_ECL + arow;
    const u16* pesh = tab + TAB_ESH + arow;
    const u16* pesl = tab + TAB_ESL + arow;

    f32x4 reA[4], imA[4];
    #pragma unroll
    for (int i = 0; i < 4; i++) {
        reA[i] = (f32x4){0.f, 0.f, 0.f, 0.f};
        imA[i] = (f32x4){0.f, 0.f, 0.f, 0.f};
    }

    int ty = tid & 63, kg = tid >> 6;
    int waddr = ((ty * 64 + kg * 16) ^ ((ty & 3) << 5));

    __syncthreads();

    for (int k0 = 0; k0 < KW; k0 += 32) {
        // ---- stage y hi/lo for this k-chunk (2048 elems, 8 per thread) ----
        {
            int kb = k0 + kg * 8;
            unsigned hb[8], lb[8];
            #pragma unroll
            for (int j = 0; j < 8; j++) {
                float y = xseg[ty + kb + j] * gsh[kb + j];
                unsigned u = __builtin_bit_cast(unsigned, y);
                unsigned h = (u + 0x7fffu + ((u >> 16) & 1u)) & 0xffff0000u;
                float hf = __builtin_bit_cast(float, h);
                float l = y - hf;
                hb[j] = h >> 16;
                lb[j] = bfbits(l);
            }
            i32x4 ph, pl;
            ph.x = (int)(hb[0] | (hb[1] << 16)); ph.y = (int)(hb[2] | (hb[3] << 16));
            ph.z = (int)(hb[4] | (hb[5] << 16)); ph.w = (int)(hb[6] | (hb[7] << 16));
            pl.x = (int)(lb[0] | (lb[1] << 16)); pl.y = (int)(lb[2] | (lb[3] << 16));
            pl.z = (int)(lb[4] | (lb[5] << 16)); pl.w = (int)(lb[6] | (lb[7] << 16));
            *(i32x4*)((char*)yH + waddr) = ph;
            *(i32x4*)((char*)yL + waddr) = pl;
        }
        __syncthreads();

        // ---- A fragments (L2-resident tables) ----
        i32x4 ech = *(const i32x4*)pech;
        i32x4 ecl = *(const i32x4*)pecl;
        i32x4 esh = *(const i32x4*)pesh;
        i32x4 esl = *(const i32x4*)pesl;
        pech += 32; pecl += 32; pesh += 32; pesl += 32;

        // ---- 4 t-tiles: 6 MFMA each ----
        #pragma unroll
        for (int tt = 0; tt < 4; tt++) {
            int tr = tt * 16 + lo;
            int raddr = ((tr * 64 + hi4 * 16) ^ ((tr & 3) << 5));
            i32x4 yh = *(const i32x4*)((char*)yH + raddr);
            i32x4 yl = *(const i32x4*)((char*)yL + raddr);
            asm("v_mfma_f32_16x16x32_bf16 %0, %1, %2, %0" : "+v"(reA[tt]) : "v"(ech), "v"(yh));
            asm("v_mfma_f32_16x16x32_bf16 %0, %1, %2, %0" : "+v"(imA[tt]) : "v"(esh), "v"(yh));
            asm("v_mfma_f32_16x16x32_bf16 %0, %1, %2, %0" : "+v"(reA[tt]) : "v"(ech), "v"(yl));
            asm("v_mfma_f32_16x16x32_bf16 %0, %1, %2, %0" : "+v"(imA[tt]) : "v"(esh), "v"(yl));
            asm("v_mfma_f32_16x16x32_bf16 %0, %1, %2, %0" : "+v"(reA[tt]) : "v"(ecl), "v"(yh));
            asm("v_mfma_f32_16x16x32_bf16 %0, %1, %2, %0" : "+v"(imA[tt]) : "v"(esl), "v"(yh));
        }
        __syncthreads();
    }
    asm volatile("s_nop 7\n\ts_nop 7");   // MFMA->VALU read hazard guard

    // ---- epilogue: S = re^2 + im^2; C layout col=lane&15(t), row=hi4*4+r(f) --
    float* dS = out + 160;
    #pragma unroll
    for (int tt = 0; tt < 4; tt++) {
        #pragma unroll
        for (int r = 0; r < 4; r++) {
            int f = f0 + wave * 16 + hi4 * 4 + r;
            float re = reA[tt][r], im = imA[tt][r];
            dS[((size_t)b << 20) + (size_t)f * 1024 + t0 + tt * 16 + lo] = re * re + im * im;
        }
    }
}

// ---------------- K3: fc1 via MFMA split-K ------------------------------------
static __device__ __forceinline__ int packbf2(float a, float b) {
    return (int)(bfbits(a) | (bfbits(b) << 16));
}
static __device__ __forceinline__ i32x4 pack8(float4 a, float4 b) {
    i32x4 r;
    r.x = packbf2(a.x, a.y); r.y = packbf2(a.z, a.w);
    r.z = packbf2(b.x, b.y); r.w = packbf2(b.z, b.w);
    return r;
}

__global__ __launch_bounds__(256, 4) void k_fc1(const float* __restrict__ S,
                                                const float* __restrict__ W1,
                                                float* __restrict__ hraw) {
    __shared__ float red[4][1024];
    int tid = threadIdx.x;
    int wave = tid >> 6, lane = tid & 63;
    int jg = wave >> 1;                          // 0..1 : j-half
    int ks = (blockIdx.x << 1) | (wave & 1);     // 0..2047 k-stripe
    int bq = lane >> 4, lo = lane & 15;

    const float* Sp = S + (size_t)lo * (1u << 20) + (size_t)ks * 512 + bq * 8;
    const float* Wp = W1 + (size_t)(jg * 64 + lo) * (1u << 20) + (size_t)ks * 512 + bq * 8;

    f32x4 acc0 = {0.f,0.f,0.f,0.f}, acc1 = acc0, acc2 = acc0, acc3 = acc0;

    for (int step = 0; step < 16; step++) {
        const float* sp = Sp + step * 32;
        const float* wp = Wp + step * 32;
        float4 a0 = *(const float4*)(sp);
        float4 a1 = *(const float4*)(sp + 4);
        float4 w00 = *(const float4*)(wp);
        float4 w01 = *(const float4*)(wp + 4);
        float4 w10 = *(const float4*)(wp + (1u << 24));          // +16 rows * 1M
        float4 w11 = *(const float4*)(wp + (1u << 24) + 4);
        float4 w20 = *(const float4*)(wp + (2u << 24));
        float4 w21 = *(const float4*)(wp + (2u << 24) + 4);
        float4 w30 = *(const float4*)(wp + (3u << 24));
        float4 w31 = *(const float4*)(wp + (3u << 24) + 4);
        i32x4 af = pack8(a0, a1);
        i32x4 b0 = pack8(w00, w01);
        i32x4 b1 = pack8(w10, w11);
        i32x4 b2 = pack8(w20, w21);
        i32x4 b3 = pack8(w30, w31);
        asm("v_mfma_f32_16x16x32_bf16 %0, %1, %2, %0" : "+v"(acc0) : "v"(af), "v"(b0));
        asm("v_mfma_f32_16x16x32_bf16 %0, %1, %2, %0" : "+v"(acc1) : "v"(af), "v"(b1));
        asm("v_mfma_f32_16x16x32_bf16 %0, %1, %2, %0" : "+v"(acc2) : "v"(af), "v"(b2));
        asm("v_mfma_f32_16x16x32_bf16 %0, %1, %2, %0" : "+v"(acc3) : "v"(af), "v"(b3));
    }
    asm volatile("s_nop 7\n\ts_nop 7");   // MFMA->VALU read hazard guard

    #pragma unroll
    for (int r = 0; r < 4; r++) {
        red[wave][(bq * 4 + r) * 64 +  0 + lo] = acc0[r];
        red[wave][(bq * 4 + r) * 64 + 16 + lo] = acc1[r];
        red[wave][(bq * 4 + r) * 64 + 32 + lo] = acc2[r];
        red[wave][(bq * 4 + r) * 64 + 48 + lo] = acc3[r];
    }
    __syncthreads();
    for (int p = tid; p < 2048; p += 256) {
        int g = p >> 10, idx = p & 1023;
        float v = red[g * 2][idx] + red[g * 2 + 1][idx];
        atomicAdd(&hraw[(idx >> 6) * HID + g * 64 + (idx & 63)], v);
    }
}

// ---------------- K4: bias+relu+fc2 head --------------------------------------
__global__ void k_head(const float* __restrict__ hraw, const float* __restrict__ b1,
                       const float* __restrict__ W2, const float* __restrict__ b2,
                       float* __restrict__ out) {
    __shared__ float hl[2048];
    int tid = threadIdx.x;
    for (int p = tid; p < 2048; p += 256) {
        float hv = hraw[p] + b1[p & 127];
        hl[p] = hv > 0.f ? hv : 0.f;
    }
    __syncthreads();
    if (tid < 160) {
        int b = tid / 10, c = tid - b * 10;
        float s = b2[c];
        for (int j = 0; j < 128; j++) s += hl[b * 128 + j] * W2[c * 128 + j];
        out[b * 10 + c] = s;
    }
}

extern "C" void kernel_launch(void* const* d_in, const int* in_sizes, int n_in,
                              void* d_out, int out_size, void* d_ws, size_t ws_size,
                              hipStream_t stream) {
    const float* x     = (const float*)d_in[0];
    const float* lambd = (const float*)d_in[1];
    const float* W1    = (const float*)d_in[2];
    const float* b1    = (const float*)d_in[3];
    const float* W2    = (const float*)d_in[4];
    const float* b2    = (const float*)d_in[5];
    float* out = (float*)d_out;
    float* ws  = (float*)d_ws;

    hipLaunchKernelGGL(k_prep,   dim3(16),          dim3(256), 0, stream, x, ws);
    hipLaunchKernelGGL(k_tables, dim3(1281),        dim3(256), 0, stream, lambd, ws);
    hipLaunchKernelGGL(k_spec,   dim3(16, 16, 16),  dim3(256), 0, stream, ws, out);
    hipLaunchKernelGGL(k_fc1,    dim3(1024),        dim3(256), 0, stream,
                       out + 160, W1, ws + OFF_HRAW);
    hipLaunchKernelGGL(k_head,   dim3(1),           dim3(256), 0, stream,
                       ws + OFF_HRAW, b1, W2, b2, out);
}